// Round 1
// baseline (361.743 us; speedup 1.0000x reference)
//
#include <hip/hip_runtime.h>
#include <hip/hip_bf16.h>
#include <stdint.h>

// Problem constants
#define M_TOK   16384        // 8 * 2048 tokens
#define EMBED   1024
#define FFN     4096
#define NQ      10

typedef __attribute__((ext_vector_type(8))) short  bf16x8;
typedef __attribute__((ext_vector_type(4))) float  f32x4;
typedef __attribute__((ext_vector_type(8))) unsigned short u16x8;

static __device__ __forceinline__ unsigned short f2bf(float f) {
    union { float f; unsigned u; } v; v.f = f;
    unsigned r = v.u + 0x7FFF + ((v.u >> 16) & 1);   // round-to-nearest-even
    return (unsigned short)(r >> 16);
}

// ---------------------------------------------------------------------------
// Kernel 1: h[t][f] = relu( sum_i cos(x[t][i]) * cos(ry[i]) * w1[f][i] ) -> bf16
// grid (128 token-tiles, 16 f-tiles), 256 threads. token tile = 128, f tile = 256.
// ---------------------------------------------------------------------------
__global__ __launch_bounds__(256) void compute_h(
    const float* __restrict__ x, const float* __restrict__ ry,
    const float* __restrict__ w1, unsigned short* __restrict__ h)
{
    __shared__ float cq[128 * NQ];   // cos(x) for 128 tokens
    __shared__ float cry[NQ];

    const int tid = threadIdx.x;
    const int t0 = blockIdx.x * 128;
    const int f0 = blockIdx.y * 256;

    if (tid < NQ) cry[tid] = cosf(ry[tid]);
    for (int idx = tid; idx < 128 * NQ; idx += 256) {
        int t = idx / NQ;
        int i = idx - t * NQ;
        cq[idx] = cosf(x[(size_t)(t0 + t) * EMBED + i]);
    }
    __syncthreads();

    const int f = f0 + tid;
    float wf[NQ];
#pragma unroll
    for (int i = 0; i < NQ; ++i) wf[i] = w1[f * NQ + i] * cry[i];

    for (int t = 0; t < 128; ++t) {
        float s = 0.f;
#pragma unroll
        for (int i = 0; i < NQ; ++i) s += cq[t * NQ + i] * wf[i];
        s = fmaxf(s, 0.f);
        h[(size_t)(t0 + t) * FFN + f] = f2bf(s);
    }
}

// ---------------------------------------------------------------------------
// Kernel 2: w2 fp32 -> bf16.  4,194,304 elems, 8 per thread.
// ---------------------------------------------------------------------------
__global__ __launch_bounds__(256) void conv_w2(
    const float* __restrict__ w2, unsigned short* __restrict__ o)
{
    const int idx = (blockIdx.x * 256 + threadIdx.x) * 8;
    float4 a = *(const float4*)(w2 + idx);
    float4 b = *(const float4*)(w2 + idx + 4);
    u16x8 v;
    v[0] = f2bf(a.x); v[1] = f2bf(a.y); v[2] = f2bf(a.z); v[3] = f2bf(a.w);
    v[4] = f2bf(b.x); v[5] = f2bf(b.y); v[6] = f2bf(b.z); v[7] = f2bf(b.w);
    *(u16x8*)(o + idx) = v;
}

// ---------------------------------------------------------------------------
// Kernel 3: C[M][N] = A[M][K] * B[N][K]^T   (bf16 in, fp32 out)
// A = h (bf16), B = w2 (bf16), C = out.
// 128x128 block tile, BK=32, 4 waves in 2x2, each wave 64x64 via 4x4 MFMA
// 16x16x32_bf16 tiles. global_load_lds width-16 staging (m97 structure).
// ---------------------------------------------------------------------------
#define GK 4096
#define GN 1024

#define GL2LDS(g, l) \
    __builtin_amdgcn_global_load_lds( \
        (const __attribute__((address_space(1))) void*)(g), \
        (__attribute__((address_space(3))) void*)(l), 16, 0, 0)

__global__ __launch_bounds__(256) void gemm_bt(
    const unsigned short* __restrict__ A,
    const unsigned short* __restrict__ B,
    float* __restrict__ C)
{
    __shared__ unsigned short At[128 * 32];   // 8 KB, row-major [128][32]
    __shared__ unsigned short Bt[128 * 32];   // 8 KB

    const int tid  = threadIdx.x;
    const int wv   = tid >> 6;
    const int lane = tid & 63;

    const int n0 = blockIdx.x * 128;   // n fast-varying: 8 blocks share an A-tile
    const int m0 = blockIdx.y * 128;

    const int wr = (wv & 1) * 64;      // wave row offset in block tile
    const int wc = (wv >> 1) * 64;     // wave col offset

    f32x4 acc[4][4] = {};

    // staging geometry: each wave-instruction covers 16 rows x 64B (1 KB).
    // lane -> row (lane>>2), 16B chunk (lane&3) within the 64B row.
    const int srow  = (lane >> 2);       // 0..15
    const int scolb = (lane & 3) * 16;   // byte offset in row

    for (int k0 = 0; k0 < GK; k0 += 32) {
#pragma unroll
        for (int j = 0; j < 2; ++j) {
            const int rt = wv * 32 + j * 16;   // tile row base for this instr
            const char* ag = (const char*)A +
                (((size_t)(m0 + rt + srow) * GK + k0) * 2 + scolb);
            GL2LDS(ag, (char*)At + rt * 64);
            const char* bg = (const char*)B +
                (((size_t)(n0 + rt + srow) * GK + k0) * 2 + scolb);
            GL2LDS(bg, (char*)Bt + rt * 64);
        }
        __syncthreads();   // compiler emits vmcnt(0) drain before barrier

        const int rA = lane & 15;          // row within 16-tile
        const int ks = (lane >> 4) * 8;    // k elems for this quad
        bf16x8 af[4], bf[4];
#pragma unroll
        for (int i = 0; i < 4; ++i) {
            af[i] = *(const bf16x8*)&At[(wr + i * 16 + rA) * 32 + ks];
            bf[i] = *(const bf16x8*)&Bt[(wc + i * 16 + rA) * 32 + ks];
        }
#pragma unroll
        for (int i = 0; i < 4; ++i)
#pragma unroll
            for (int j = 0; j < 4; ++j)
                acc[i][j] = __builtin_amdgcn_mfma_f32_16x16x32_bf16(
                    af[i], bf[j], acc[i][j], 0, 0, 0);
        __syncthreads();
    }

    // epilogue: C/D layout col = lane&15, row = (lane>>4)*4 + reg
    const int cn    = lane & 15;
    const int rbase = (lane >> 4) * 4;
#pragma unroll
    for (int i = 0; i < 4; ++i)
#pragma unroll
        for (int j = 0; j < 4; ++j)
#pragma unroll
            for (int r = 0; r < 4; ++r) {
                const int m = m0 + wr + i * 16 + rbase + r;
                const int n = n0 + wc + j * 16 + cn;
                C[(size_t)m * GN + n] = acc[i][j][r];
            }
}

// ---------------------------------------------------------------------------
extern "C" void kernel_launch(void* const* d_in, const int* in_sizes, int n_in,
                              void* d_out, int out_size, void* d_ws, size_t ws_size,
                              hipStream_t stream) {
    const float* x  = (const float*)d_in[0];
    const float* ry = (const float*)d_in[1];
    const float* w1 = (const float*)d_in[2];
    const float* w2 = (const float*)d_in[3];
    float* out = (float*)d_out;

    unsigned short* h   = (unsigned short*)d_ws;                       // 128 MiB
    unsigned short* w2b = (unsigned short*)((char*)d_ws +
                           (size_t)M_TOK * FFN * sizeof(unsigned short));

    compute_h<<<dim3(128, 16), 256, 0, stream>>>(x, ry, w1, h);
    conv_w2<<<dim3((EMBED * FFN) / (256 * 8)), 256, 0, stream>>>(w2, w2b);
    gemm_bt<<<dim3(GN / 128, M_TOK / 128), 256, 0, stream>>>(h, w2b, out);
}